// Round 1
// baseline (422.710 us; speedup 1.0000x reference)
//
#include <hip/hip_runtime.h>
#include <math.h>

#define NN 100000
#define NE 1600000
#define F_IN 64
#define HID 16
#define OUTF 32

// ---------------- layer-1 projection: a1 = x@W1[0], b1 = x@W1[1] ----------------
__global__ __launch_bounds__(256) void proj1_kernel(const float* __restrict__ x,
                                                    const float* __restrict__ W1,
                                                    float* __restrict__ a1,
                                                    float* __restrict__ b1) {
    __shared__ float w[2 * F_IN * HID];  // 2048 floats = 8 KB
    for (int i = threadIdx.x; i < 2 * F_IN * HID; i += 256) w[i] = W1[i];
    __syncthreads();
    int n = blockIdx.x * 256 + threadIdx.x;
    if (n >= NN) return;
    float accA[HID], accB[HID];
#pragma unroll
    for (int o = 0; o < HID; ++o) { accA[o] = 0.f; accB[o] = 0.f; }
    const float* xr = x + (size_t)n * F_IN;
    for (int f = 0; f < F_IN; ++f) {
        float xv = xr[f];
        const float* w0 = &w[f * HID];
        const float* w1 = &w[F_IN * HID + f * HID];
#pragma unroll
        for (int o = 0; o < HID; ++o) {
            accA[o] = fmaf(xv, w0[o], accA[o]);
            accB[o] = fmaf(xv, w1[o], accB[o]);
        }
    }
    float* ar = a1 + (size_t)n * HID;
    float* br = b1 + (size_t)n * HID;
#pragma unroll
    for (int o = 0; o < HID; ++o) { ar[o] = accA[o]; br[o] = accB[o]; }
}

// ---------------- layer-1 edge scatter (+degree) ----------------
__global__ __launch_bounds__(256) void scatter1_kernel(const int* __restrict__ ei,
                                                       const float* __restrict__ ea,
                                                       const float* __restrict__ a1,
                                                       const float* __restrict__ b1,
                                                       float* __restrict__ accum1,
                                                       float* __restrict__ deg) {
    long long gid = (long long)blockIdx.x * 256 + threadIdx.x;
    int e = (int)(gid >> 4);
    int j = (int)(gid & 15);
    if (e >= NE) return;
    int src = ei[e];
    int dst = ei[NE + e];
    float u = ea[e];
    float av = a1[src * HID + j];
    float bv = b1[src * HID + j];
    float msg = av + u * (bv - av);  // (1-u)*a + u*b
    atomicAdd(&accum1[dst * HID + j], msg);
    if (j == 0) atomicAdd(&deg[dst], 1.0f);
}

// ---------------- layer-1 epilogue: mean + root + bias + ELU -> h ----------------
__global__ __launch_bounds__(256) void finalize1_kernel(const float* __restrict__ accum1,
                                                        const float* __restrict__ deg,
                                                        const float* __restrict__ x,
                                                        const float* __restrict__ root1,
                                                        const float* __restrict__ bias1,
                                                        float* __restrict__ h) {
    __shared__ float w[F_IN * HID];  // 1024
    __shared__ float bb[HID];
    for (int i = threadIdx.x; i < F_IN * HID; i += 256) w[i] = root1[i];
    if (threadIdx.x < HID) bb[threadIdx.x] = bias1[threadIdx.x];
    __syncthreads();
    int n = blockIdx.x * 256 + threadIdx.x;
    if (n >= NN) return;
    float inv = 1.0f / fmaxf(deg[n], 1.0f);
    float acc[HID];
#pragma unroll
    for (int o = 0; o < HID; ++o) acc[o] = accum1[(size_t)n * HID + o] * inv + bb[o];
    const float* xr = x + (size_t)n * F_IN;
    for (int f = 0; f < F_IN; ++f) {
        float xv = xr[f];
#pragma unroll
        for (int o = 0; o < HID; ++o) acc[o] = fmaf(xv, w[f * HID + o], acc[o]);
    }
    float* hr = h + (size_t)n * HID;
#pragma unroll
    for (int o = 0; o < HID; ++o) {
        float v = acc[o];
        hr[o] = v > 0.f ? v : expm1f(v);  // ELU(alpha=1)
    }
}

// ---------------- layer-2 projection: a2 = h@W2[0], b2 = h@W2[1] ----------------
__global__ __launch_bounds__(256) void proj2_kernel(const float* __restrict__ h,
                                                    const float* __restrict__ W2,
                                                    float* __restrict__ a2,
                                                    float* __restrict__ b2) {
    __shared__ float w[2 * HID * OUTF];  // 1024
    for (int i = threadIdx.x; i < 2 * HID * OUTF; i += 256) w[i] = W2[i];
    __syncthreads();
    int n = blockIdx.x * 256 + threadIdx.x;
    if (n >= NN) return;
    float accA[OUTF], accB[OUTF];
#pragma unroll
    for (int o = 0; o < OUTF; ++o) { accA[o] = 0.f; accB[o] = 0.f; }
    const float* hr = h + (size_t)n * HID;
#pragma unroll
    for (int f = 0; f < HID; ++f) {
        float hv = hr[f];
        const float* w0 = &w[f * OUTF];
        const float* w1 = &w[HID * OUTF + f * OUTF];
#pragma unroll
        for (int o = 0; o < OUTF; ++o) {
            accA[o] = fmaf(hv, w0[o], accA[o]);
            accB[o] = fmaf(hv, w1[o], accB[o]);
        }
    }
    float* ar = a2 + (size_t)n * OUTF;
    float* br = b2 + (size_t)n * OUTF;
#pragma unroll
    for (int o = 0; o < OUTF; ++o) { ar[o] = accA[o]; br[o] = accB[o]; }
}

// ---------------- layer-2 edge scatter ----------------
__global__ __launch_bounds__(256) void scatter2_kernel(const int* __restrict__ ei,
                                                       const float* __restrict__ ea,
                                                       const float* __restrict__ a2,
                                                       const float* __restrict__ b2,
                                                       float* __restrict__ accum2) {
    long long gid = (long long)blockIdx.x * 256 + threadIdx.x;
    int e = (int)(gid >> 5);
    int j = (int)(gid & 31);
    if (e >= NE) return;
    int src = ei[e];
    int dst = ei[NE + e];
    float u = ea[e];
    float av = a2[src * OUTF + j];
    float bv = b2[src * OUTF + j];
    float msg = av + u * (bv - av);
    atomicAdd(&accum2[dst * OUTF + j], msg);
}

// ---------------- layer-2 epilogue: mean + root + bias + log_softmax -> out ----------------
__global__ __launch_bounds__(256) void finalize2_kernel(const float* __restrict__ accum2,
                                                        const float* __restrict__ deg,
                                                        const float* __restrict__ h,
                                                        const float* __restrict__ root2,
                                                        const float* __restrict__ bias2,
                                                        float* __restrict__ out) {
    __shared__ float w[HID * OUTF];  // 512
    __shared__ float bb[OUTF];
    for (int i = threadIdx.x; i < HID * OUTF; i += 256) w[i] = root2[i];
    if (threadIdx.x < OUTF) bb[threadIdx.x] = bias2[threadIdx.x];
    __syncthreads();
    int n = blockIdx.x * 256 + threadIdx.x;
    if (n >= NN) return;
    float inv = 1.0f / fmaxf(deg[n], 1.0f);
    float acc[OUTF];
#pragma unroll
    for (int o = 0; o < OUTF; ++o) acc[o] = accum2[(size_t)n * OUTF + o] * inv + bb[o];
    const float* hr = h + (size_t)n * HID;
#pragma unroll
    for (int f = 0; f < HID; ++f) {
        float hv = hr[f];
#pragma unroll
        for (int o = 0; o < OUTF; ++o) acc[o] = fmaf(hv, w[f * OUTF + o], acc[o]);
    }
    float m = -INFINITY;
#pragma unroll
    for (int o = 0; o < OUTF; ++o) m = fmaxf(m, acc[o]);
    float s = 0.f;
#pragma unroll
    for (int o = 0; o < OUTF; ++o) s += expf(acc[o] - m);
    float lse = m + logf(s);
    float* outr = out + (size_t)n * OUTF;
#pragma unroll
    for (int o = 0; o < OUTF; ++o) outr[o] = acc[o] - lse;
}

extern "C" void kernel_launch(void* const* d_in, const int* in_sizes, int n_in,
                              void* d_out, int out_size, void* d_ws, size_t ws_size,
                              hipStream_t stream) {
    const float* x     = (const float*)d_in[0];
    const int*   ei    = (const int*)d_in[1];   // edge_index (2, E): row0=src, row1=dst
    // d_in[2] = dropout (unused, =0)
    const float* ea    = (const float*)d_in[3];
    const float* W1    = (const float*)d_in[4];
    const float* root1 = (const float*)d_in[5];
    const float* bias1 = (const float*)d_in[6];
    const float* W2    = (const float*)d_in[7];
    const float* root2 = (const float*)d_in[8];
    const float* bias2 = (const float*)d_in[9];
    float* out = (float*)d_out;
    float* ws  = (float*)d_ws;

    const size_t N = NN;
    // workspace layout (floats), total 113*N = 45.2 MB
    float* deg    = ws;             // [0, N)
    float* h      = ws + N;         // [N, 17N)
    float* accum2 = ws + 17 * N;    // [17N, 49N)
    float* a1     = ws + 49 * N;    // [49N, 65N)
    float* b1     = ws + 65 * N;    // [65N, 81N)
    float* accum1 = ws + 81 * N;    // [81N, 97N)  (dead after finalize1)
    float* a2     = ws + 49 * N;    // aliases a1/b1
    float* b2     = ws + 81 * N;    // aliases accum1 + beyond

    hipMemsetAsync(deg, 0, N * sizeof(float), stream);
    hipMemsetAsync(accum1, 0, 16 * N * sizeof(float), stream);
    hipMemsetAsync(accum2, 0, 32 * N * sizeof(float), stream);

    int nb_nodes = (NN + 255) / 256;
    proj1_kernel<<<nb_nodes, 256, 0, stream>>>(x, W1, a1, b1);
    scatter1_kernel<<<(NE * 16 + 255) / 256, 256, 0, stream>>>(ei, ea, a1, b1, accum1, deg);
    finalize1_kernel<<<nb_nodes, 256, 0, stream>>>(accum1, deg, x, root1, bias1, h);
    proj2_kernel<<<nb_nodes, 256, 0, stream>>>(h, W2, a2, b2);
    scatter2_kernel<<<(NE * 32 + 255) / 256, 256, 0, stream>>>(ei, ea, a2, b2, accum2);
    finalize2_kernel<<<nb_nodes, 256, 0, stream>>>(accum2, deg, h, root2, bias2, out);
}

// Round 2
// 398.463 us; speedup vs baseline: 1.0609x; 1.0609x over previous
//
#include <hip/hip_runtime.h>
#include <math.h>

#define NN 100000
#define NE 1600000
#define F_IN 64
#define HID 16
#define OUTF 32
#define NBLK ((NN + 255) / 256)   // 391

// ---------------- CSR build ----------------
__global__ __launch_bounds__(256) void hist_kernel(const int* __restrict__ ei,
                                                   int* __restrict__ cnt) {
    int e = blockIdx.x * 256 + threadIdx.x;
    if (e >= NE) return;
    atomicAdd(&cnt[ei[NE + e]], 1);
}

__global__ __launch_bounds__(256) void scan_block_kernel(const int* __restrict__ cnt,
                                                         int* __restrict__ rowptr,
                                                         int* __restrict__ partial) {
    __shared__ int s[256];
    int t = threadIdx.x;
    int i = blockIdx.x * 256 + t;
    int v = (i < NN) ? cnt[i] : 0;
    s[t] = v;
    __syncthreads();
    for (int off = 1; off < 256; off <<= 1) {
        int x = (t >= off) ? s[t - off] : 0;
        __syncthreads();
        s[t] += x;
        __syncthreads();
    }
    if (i < NN) rowptr[i] = s[t] - v;            // exclusive
    if (t == 255) partial[blockIdx.x] = s[255];  // block total
}

__global__ __launch_bounds__(512) void scan_top_kernel(int* __restrict__ partial) {
    __shared__ int s[512];
    int t = threadIdx.x;
    int v = (t < NBLK) ? partial[t] : 0;
    s[t] = v;
    __syncthreads();
    for (int off = 1; off < 512; off <<= 1) {
        int x = (t >= off) ? s[t - off] : 0;
        __syncthreads();
        s[t] += x;
        __syncthreads();
    }
    if (t < NBLK) partial[t] = s[t] - v;  // exclusive block offsets
}

__global__ __launch_bounds__(256) void scan_add_kernel(int* __restrict__ rowptr,
                                                       const int* __restrict__ partial) {
    int i = blockIdx.x * 256 + threadIdx.x;
    if (i < NN) rowptr[i] += partial[blockIdx.x];
    if (i == 0) rowptr[NN] = NE;
}

// reorder edges into CSR order; pack (src, u) as int2 for one 8B write/read
__global__ __launch_bounds__(256) void reorder_kernel(const int* __restrict__ ei,
                                                      const float* __restrict__ ea,
                                                      const int* __restrict__ rowptr,
                                                      int* __restrict__ cursor,
                                                      int2* __restrict__ su) {
    int e = blockIdx.x * 256 + threadIdx.x;
    if (e >= NE) return;
    int src = ei[e];
    int dst = ei[NE + e];
    float u = ea[e];
    int p = rowptr[dst] + atomicAdd(&cursor[dst], 1);
    su[p] = make_int2(src, __float_as_int(u));
}

// ---------------- layer-1 projection: ab1[n][j] = (a, b-a) ----------------
__global__ __launch_bounds__(256) void proj1_kernel(const float* __restrict__ x,
                                                    const float* __restrict__ W1,
                                                    float2* __restrict__ ab1) {
    __shared__ float w[2 * F_IN * HID];
    for (int i = threadIdx.x; i < 2 * F_IN * HID; i += 256) w[i] = W1[i];
    __syncthreads();
    int n = blockIdx.x * 256 + threadIdx.x;
    if (n >= NN) return;
    float accA[HID], accB[HID];
#pragma unroll
    for (int o = 0; o < HID; ++o) { accA[o] = 0.f; accB[o] = 0.f; }
    const float* xr = x + (size_t)n * F_IN;
    for (int f = 0; f < F_IN; ++f) {
        float xv = xr[f];
        const float* w0 = &w[f * HID];
        const float* w1 = &w[F_IN * HID + f * HID];
#pragma unroll
        for (int o = 0; o < HID; ++o) {
            accA[o] = fmaf(xv, w0[o], accA[o]);
            accB[o] = fmaf(xv, w1[o], accB[o]);
        }
    }
    float2* ar = ab1 + (size_t)n * HID;
#pragma unroll
    for (int o = 0; o < HID; ++o) ar[o] = make_float2(accA[o], accB[o] - accA[o]);
}

// ---------------- layer-1 gather-reduce + mean + root + bias + ELU -> h ----------------
__global__ __launch_bounds__(256) void gather1_kernel(const int* __restrict__ rowptr,
                                                      const int2* __restrict__ su,
                                                      const float2* __restrict__ ab1,
                                                      const float* __restrict__ x,
                                                      const float* __restrict__ root1,
                                                      const float* __restrict__ bias1,
                                                      float* __restrict__ h) {
    __shared__ float w[F_IN * HID];
    __shared__ float bb[HID];
    for (int i = threadIdx.x; i < F_IN * HID; i += 256) w[i] = root1[i];
    if (threadIdx.x < HID) bb[threadIdx.x] = bias1[threadIdx.x];
    __syncthreads();
    int n = blockIdx.x * 16 + (threadIdx.x >> 4);
    int j = threadIdx.x & 15;
    if (n >= NN) return;
    int beg = rowptr[n], end = rowptr[n + 1];
    float acc = 0.f;
    for (int e = beg; e < end; ++e) {
        int2 s = su[e];
        float u = __int_as_float(s.y);
        float2 ab = ab1[(size_t)s.x * HID + j];
        acc = fmaf(u, ab.y, acc + ab.x);
    }
    float inv = 1.0f / (float)max(end - beg, 1);
    float v = acc * inv + bb[j];
    const float* xr = x + (size_t)n * F_IN;
    for (int f = 0; f < F_IN; ++f) v = fmaf(xr[f], w[f * HID + j], v);
    h[(size_t)n * HID + j] = v > 0.f ? v : expm1f(v);
}

// ---------------- layer-2 projection ----------------
__global__ __launch_bounds__(256) void proj2_kernel(const float* __restrict__ h,
                                                    const float* __restrict__ W2,
                                                    float2* __restrict__ ab2) {
    __shared__ float w[2 * HID * OUTF];
    for (int i = threadIdx.x; i < 2 * HID * OUTF; i += 256) w[i] = W2[i];
    __syncthreads();
    int n = blockIdx.x * 256 + threadIdx.x;
    if (n >= NN) return;
    float accA[OUTF], accB[OUTF];
#pragma unroll
    for (int o = 0; o < OUTF; ++o) { accA[o] = 0.f; accB[o] = 0.f; }
    const float* hr = h + (size_t)n * HID;
#pragma unroll
    for (int f = 0; f < HID; ++f) {
        float hv = hr[f];
        const float* w0 = &w[f * OUTF];
        const float* w1 = &w[HID * OUTF + f * OUTF];
#pragma unroll
        for (int o = 0; o < OUTF; ++o) {
            accA[o] = fmaf(hv, w0[o], accA[o]);
            accB[o] = fmaf(hv, w1[o], accB[o]);
        }
    }
    float2* ar = ab2 + (size_t)n * OUTF;
#pragma unroll
    for (int o = 0; o < OUTF; ++o) ar[o] = make_float2(accA[o], accB[o] - accA[o]);
}

// ---------------- layer-2 gather-reduce + mean + root + bias + log_softmax -> out ----------------
__global__ __launch_bounds__(256) void gather2_kernel(const int* __restrict__ rowptr,
                                                      const int2* __restrict__ su,
                                                      const float2* __restrict__ ab2,
                                                      const float* __restrict__ h,
                                                      const float* __restrict__ root2,
                                                      const float* __restrict__ bias2,
                                                      float* __restrict__ out) {
    __shared__ float w[HID * OUTF];
    __shared__ float bb[OUTF];
    for (int i = threadIdx.x; i < HID * OUTF; i += 256) w[i] = root2[i];
    if (threadIdx.x < OUTF) bb[threadIdx.x] = bias2[threadIdx.x];
    __syncthreads();
    int n = blockIdx.x * 8 + (threadIdx.x >> 5);
    int j = threadIdx.x & 31;
    if (n >= NN) return;
    int beg = rowptr[n], end = rowptr[n + 1];
    float acc = 0.f;
    for (int e = beg; e < end; ++e) {
        int2 s = su[e];
        float u = __int_as_float(s.y);
        float2 ab = ab2[(size_t)s.x * OUTF + j];
        acc = fmaf(u, ab.y, acc + ab.x);
    }
    float inv = 1.0f / (float)max(end - beg, 1);
    float v = acc * inv + bb[j];
    const float* hr = h + (size_t)n * HID;
#pragma unroll
    for (int f = 0; f < HID; ++f) v = fmaf(hr[f], w[f * OUTF + j], v);
    // log_softmax across the node's 32 lanes (within half-wave)
    float m = v;
#pragma unroll
    for (int mask = 16; mask >= 1; mask >>= 1) m = fmaxf(m, __shfl_xor(m, mask));
    float ex = expf(v - m);
    float s = ex;
#pragma unroll
    for (int mask = 16; mask >= 1; mask >>= 1) s += __shfl_xor(s, mask);
    out[(size_t)n * OUTF + j] = v - m - logf(s);
}

extern "C" void kernel_launch(void* const* d_in, const int* in_sizes, int n_in,
                              void* d_out, int out_size, void* d_ws, size_t ws_size,
                              hipStream_t stream) {
    const float* x     = (const float*)d_in[0];
    const int*   ei    = (const int*)d_in[1];
    const float* ea    = (const float*)d_in[3];
    const float* W1    = (const float*)d_in[4];
    const float* root1 = (const float*)d_in[5];
    const float* bias1 = (const float*)d_in[6];
    const float* W2    = (const float*)d_in[7];
    const float* root2 = (const float*)d_in[8];
    const float* bias2 = (const float*)d_in[9];
    float* out = (float*)d_out;
    float* ws  = (float*)d_ws;

    const size_t N = NN;
    // workspace layout (float units), total ~116N = 46.4 MB
    int*    cnt     = (int*)(ws);                 // [0, N)
    int*    cursor  = (int*)(ws + N);             // [N, 2N)
    int*    rowptr  = (int*)(ws + 2 * N);         // [2N, 3N+1)
    int*    partial = (int*)(ws + 3 * N + 256);   // 512 ints
    float*  h       = ws + 4 * N;                 // [4N, 20N)
    int2*   su      = (int2*)(ws + 20 * N);       // [20N, 52N)  E * 8B
    float2* ab1     = (float2*)(ws + 52 * N);     // [52N, 84N)  16N float2
    float2* ab2     = (float2*)(ws + 52 * N);     // [52N, 116N) 32N float2 (reuses ab1)

    hipMemsetAsync(cnt, 0, N * sizeof(int), stream);
    hipMemsetAsync(cursor, 0, N * sizeof(int), stream);

    int nbE = (NE + 255) / 256;
    hist_kernel<<<nbE, 256, 0, stream>>>(ei, cnt);
    scan_block_kernel<<<NBLK, 256, 0, stream>>>(cnt, rowptr, partial);
    scan_top_kernel<<<1, 512, 0, stream>>>(partial);
    scan_add_kernel<<<NBLK, 256, 0, stream>>>(rowptr, partial);
    reorder_kernel<<<nbE, 256, 0, stream>>>(ei, ea, rowptr, cursor, su);

    proj1_kernel<<<NBLK, 256, 0, stream>>>(x, W1, ab1);
    gather1_kernel<<<(NN + 15) / 16, 256, 0, stream>>>(rowptr, su, ab1, x, root1, bias1, h);
    proj2_kernel<<<NBLK, 256, 0, stream>>>(h, W2, ab2);
    gather2_kernel<<<(NN + 7) / 8, 256, 0, stream>>>(rowptr, su, ab2, h, root2, bias2, out);
}